// Round 1
// baseline (1401.489 us; speedup 1.0000x reference)
//
#include <hip/hip_runtime.h>
#include <math.h>

#define B_   8192
#define F_   48
#define T_   512
#define L_   8
#define RPB  16      // rows per block for GEMM kernels
#define CT   64      // t-chunk staged in LDS
#define AST  49      // LDS stride for A chunks (odd -> conflict-free)
#define ZST  49      // LDS stride for z rows
#define NB_G (B_/RPB)   // 512 blocks for GEMM kernels
#define NB_I 1024       // blocks for init kernel

// ---------------- init: z = u, H = 0, partial ||z||^2 ----------------
__global__ __launch_bounds__(256) void k_init(
    const float* __restrict__ u, float* __restrict__ z_re, float* __restrict__ z_im,
    float* __restrict__ H_re, float* __restrict__ H_im, float* __restrict__ part)
{
    __shared__ float red[256];
    const int tid = threadIdx.x;
    const int gtid = blockIdx.x * 256 + tid;
    const int stride = gridDim.x * 256;
    float acc = 0.f;
    for (int i = gtid; i < B_ * F_; i += stride) {
        float ur = u[2 * i], ui = u[2 * i + 1];
        z_re[i] = ur; z_im[i] = ui;
        acc += ur * ur + ui * ui;
    }
    for (int i = gtid; i < B_ * T_; i += stride) { H_re[i] = 0.f; H_im[i] = 0.f; }
    red[tid] = acc; __syncthreads();
    for (int s = 128; s > 0; s >>= 1) { if (tid < s) red[tid] += red[tid + s]; __syncthreads(); }
    if (tid == 0) part[blockIdx.x] = red[0];
}

// ---------------- combine sigma ----------------
__global__ __launch_bounds__(256) void k_combine_sigma(
    const float* __restrict__ part, int n, float* __restrict__ scal)
{
    __shared__ float red[256];
    const int tid = threadIdx.x;
    float s = 0.f;
    for (int i = tid; i < n; i += 256) s += part[i];
    red[tid] = s; __syncthreads();
    for (int st = 128; st > 0; st >>= 1) { if (tid < st) red[tid] += red[tid + st]; __syncthreads(); }
    if (tid == 0) scal[0] = sqrtf(red[0]) / sqrtf(48.0f);
}

// ---------------- combine b ----------------
__global__ __launch_bounds__(256) void k_combine_b(
    const float* __restrict__ pr, const float* __restrict__ pi, int n,
    const float* __restrict__ th, float* __restrict__ scal)
{
    __shared__ float red[256];
    const int tid = threadIdx.x;
    float sr = 0.f, si = 0.f;
    for (int i = tid; i < n; i += 256) { sr += pr[i]; si += pi[i]; }
    red[tid] = sr; __syncthreads();
    for (int st = 128; st > 0; st >>= 1) { if (tid < st) red[tid] += red[tid + st]; __syncthreads(); }
    float tr = red[0]; __syncthreads();
    red[tid] = si; __syncthreads();
    for (int st = 128; st > 0; st >>= 1) { if (tid < st) red[tid] += red[tid + st]; __syncthreads(); }
    if (tid == 0) {
        float th1 = th[1];
        scal[1] = th1 * tr / 48.0f;
        scal[2] = th1 * red[0] / 48.0f;
    }
}

// ---------------- forward: Z = z@A^T, R = H + Z, act -> Hn (stored in H), df partials ----------------
__global__ __launch_bounds__(256) void k_forward(
    const float* __restrict__ z_re, const float* __restrict__ z_im,
    float* __restrict__ H_re, float* __restrict__ H_im,
    const float* __restrict__ Ar, const float* __restrict__ Ai,
    const float* __restrict__ th, const float* __restrict__ scal,
    float* __restrict__ part_r, float* __restrict__ part_i)
{
    __shared__ float ar_sh[CT * AST];
    __shared__ float ai_sh[CT * AST];
    __shared__ float zr_sh[RPB * ZST];
    __shared__ float zi_sh[RPB * ZST];
    __shared__ float red[256];
    const int tid = threadIdx.x;
    const int row0 = blockIdx.x * RPB;

    // stage z rows
    for (int idx = tid; idx < RPB * F_; idx += 256) {
        int r = idx / F_, f = idx - r * F_;
        int g = (row0 + r) * F_ + f;
        zr_sh[r * ZST + f] = z_re[g];
        zi_sh[r * ZST + f] = z_im[g];
    }
    const float lam = th[0] * scal[0];
    const float th1 = th[1];
    float cr = 0.f, ci = 0.f;

    const int tq = tid & 31;    // t-pair index within chunk
    const int rg = tid >> 5;    // 0..7 -> local rows rg*2, rg*2+1
    const float* zr0 = &zr_sh[(rg * 2) * ZST];
    const float* zr1 = &zr_sh[(rg * 2 + 1) * ZST];
    const float* zi0 = &zi_sh[(rg * 2) * ZST];
    const float* zi1 = &zi_sh[(rg * 2 + 1) * ZST];

    for (int tc = 0; tc < T_; tc += CT) {
        __syncthreads();   // prev compute done (and z visible on first iter)
        for (int idx = tid; idx < CT * F_; idx += 256) {
            int t = idx / F_, f = idx - t * F_;
            int g = (tc + t) * F_ + f;
            ar_sh[t * AST + f] = Ar[g];
            ai_sh[t * AST + f] = Ai[g];
        }
        __syncthreads();

        const float* a0r = &ar_sh[(tq * 2) * AST];
        const float* a1r = &ar_sh[(tq * 2 + 1) * AST];
        const float* a0i = &ai_sh[(tq * 2) * AST];
        const float* a1i = &ai_sh[(tq * 2 + 1) * AST];
        float aR00 = 0.f, aR01 = 0.f, aR10 = 0.f, aR11 = 0.f;
        float aI00 = 0.f, aI01 = 0.f, aI10 = 0.f, aI11 = 0.f;
        #pragma unroll 8
        for (int f = 0; f < F_; ++f) {
            float z0r = zr0[f], z0i = zi0[f];
            float z1r = zr1[f], z1i = zi1[f];
            float b0r = a0r[f], b0i = a0i[f];
            float b1r = a1r[f], b1i = a1i[f];
            aR00 += z0r * b0r; aR00 -= z0i * b0i;
            aI00 += z0r * b0i; aI00 += z0i * b0r;
            aR01 += z0r * b1r; aR01 -= z0i * b1i;
            aI01 += z0r * b1i; aI01 += z0i * b1r;
            aR10 += z1r * b0r; aR10 -= z1i * b0i;
            aI10 += z1r * b0i; aI10 += z1i * b0r;
            aR11 += z1r * b1r; aR11 -= z1i * b1i;
            aI11 += z1r * b1i; aI11 += z1i * b1r;
        }
        // write back R -> act -> Hn
        const int t = tc + tq * 2;
        #pragma unroll
        for (int ri = 0; ri < 2; ++ri) {
            int r = row0 + rg * 2 + ri;
            float2* hre = (float2*)&H_re[(size_t)r * T_ + t];
            float2* him = (float2*)&H_im[(size_t)r * T_ + t];
            float2 hr = *hre, hi = *him;
            float Rr0 = hr.x + (ri == 0 ? aR00 : aR10);
            float Rr1 = hr.y + (ri == 0 ? aR01 : aR11);
            float Ri0 = hi.x + (ri == 0 ? aI00 : aI10);
            float Ri1 = hi.y + (ri == 0 ? aI01 : aI11);
            float m, sh, sg;
            m = fabsf(Rr0); sh = fmaxf(m - lam, 0.f);
            sg = (Rr0 > 0.f) ? 1.f : ((Rr0 < 0.f) ? -1.f : 0.f);
            float f0 = th1 * sg * sh; cr += (m > lam) ? 1.f : 0.f;
            m = fabsf(Rr1); sh = fmaxf(m - lam, 0.f);
            sg = (Rr1 > 0.f) ? 1.f : ((Rr1 < 0.f) ? -1.f : 0.f);
            float f1 = th1 * sg * sh; cr += (m > lam) ? 1.f : 0.f;
            m = fabsf(Ri0); sh = fmaxf(m - lam, 0.f);
            sg = (Ri0 > 0.f) ? 1.f : ((Ri0 < 0.f) ? -1.f : 0.f);
            float g0 = th1 * sg * sh; ci += (m > lam) ? 1.f : 0.f;
            m = fabsf(Ri1); sh = fmaxf(m - lam, 0.f);
            sg = (Ri1 > 0.f) ? 1.f : ((Ri1 < 0.f) ? -1.f : 0.f);
            float g1 = th1 * sg * sh; ci += (m > lam) ? 1.f : 0.f;
            *hre = make_float2(f0, f1);
            *him = make_float2(g0, g1);
        }
    }
    __syncthreads();
    red[tid] = cr; __syncthreads();
    for (int s = 128; s > 0; s >>= 1) { if (tid < s) red[tid] += red[tid + s]; __syncthreads(); }
    if (tid == 0) part_r[blockIdx.x] = red[0];
    __syncthreads();
    red[tid] = ci; __syncthreads();
    for (int s = 128; s > 0; s >>= 1) { if (tid < s) red[tid] += red[tid + s]; __syncthreads(); }
    if (tid == 0) part_i[blockIdx.x] = red[0];
}

// ---------------- backward: h = Hn@A, zn = u - h + b*z, partial ||zn||^2 ----------------
__global__ __launch_bounds__(256) void k_backward(
    float* __restrict__ z_re, float* __restrict__ z_im,
    const float* __restrict__ H_re, const float* __restrict__ H_im,
    const float* __restrict__ Ar, const float* __restrict__ Ai,
    const float* __restrict__ u, const float* __restrict__ scal,
    float* __restrict__ part_sig)
{
    __shared__ float ar_sh[CT * AST];
    __shared__ float ai_sh[CT * AST];
    __shared__ float hr_sh[RPB * CT];
    __shared__ float hi_sh[RPB * CT];
    __shared__ float red[256];
    const int tid = threadIdx.x;
    const int row0 = blockIdx.x * RPB;
    const int fl = tid & 63;
    const int rg = tid >> 6;    // 0..3 -> local rows rg*4 .. rg*4+3
    float hR[4] = {0.f, 0.f, 0.f, 0.f};
    float hI[4] = {0.f, 0.f, 0.f, 0.f};

    for (int tc = 0; tc < T_; tc += CT) {
        __syncthreads();
        for (int idx = tid; idx < CT * F_; idx += 256) {
            int t = idx / F_, f = idx - t * F_;
            int g = (tc + t) * F_ + f;
            ar_sh[t * AST + f] = Ar[g];
            ai_sh[t * AST + f] = Ai[g];
        }
        for (int idx = tid; idx < RPB * CT; idx += 256) {
            int r = idx >> 6, t = idx & (CT - 1);
            int g = (row0 + r) * T_ + tc + t;
            hr_sh[r * CT + t] = H_re[g];
            hi_sh[r * CT + t] = H_im[g];
        }
        __syncthreads();
        if (fl < F_) {
            #pragma unroll 4
            for (int t = 0; t < CT; ++t) {
                float br = ar_sh[t * AST + fl];
                float bi = ai_sh[t * AST + fl];
                #pragma unroll
                for (int k = 0; k < 4; ++k) {
                    float hr = hr_sh[(rg * 4 + k) * CT + t];
                    float hi = hi_sh[(rg * 4 + k) * CT + t];
                    hR[k] += hr * br; hR[k] -= hi * bi;
                    hI[k] += hr * bi; hI[k] += hi * br;
                }
            }
        }
    }
    float nrm = 0.f;
    if (fl < F_) {
        const float br = scal[1], bi = scal[2];
        #pragma unroll
        for (int k = 0; k < 4; ++k) {
            int r = row0 + rg * 4 + k;
            int gi = r * F_ + fl;
            float zr = z_re[gi], zi = z_im[gi];
            float ur = u[2 * gi], ui = u[2 * gi + 1];
            float znr = ur - hR[k] + br * zr;
            float zni = ui - hI[k] + bi * zi;
            z_re[gi] = znr; z_im[gi] = zni;
            nrm += znr * znr + zni * zni;
        }
    }
    __syncthreads();
    red[tid] = nrm; __syncthreads();
    for (int s = 128; s > 0; s >>= 1) { if (tid < s) red[tid] += red[tid + s]; __syncthreads(); }
    if (tid == 0) part_sig[blockIdx.x] = red[0];
}

// ---------------- final: out = stack(H @ DFT) ----------------
__global__ __launch_bounds__(256) void k_final(
    const float* __restrict__ H_re, const float* __restrict__ H_im,
    const float* __restrict__ Dr, const float* __restrict__ Di,
    float* __restrict__ out)
{
    __shared__ float ar_sh[CT * AST];
    __shared__ float ai_sh[CT * AST];
    __shared__ float hr_sh[RPB * CT];
    __shared__ float hi_sh[RPB * CT];
    const int tid = threadIdx.x;
    const int row0 = blockIdx.x * RPB;
    const int fl = tid & 63;
    const int rg = tid >> 6;
    float hR[4] = {0.f, 0.f, 0.f, 0.f};
    float hI[4] = {0.f, 0.f, 0.f, 0.f};

    for (int tc = 0; tc < T_; tc += CT) {
        __syncthreads();
        for (int idx = tid; idx < CT * F_; idx += 256) {
            int t = idx / F_, f = idx - t * F_;
            int g = (tc + t) * F_ + f;
            ar_sh[t * AST + f] = Dr[g];
            ai_sh[t * AST + f] = Di[g];
        }
        for (int idx = tid; idx < RPB * CT; idx += 256) {
            int r = idx >> 6, t = idx & (CT - 1);
            int g = (row0 + r) * T_ + tc + t;
            hr_sh[r * CT + t] = H_re[g];
            hi_sh[r * CT + t] = H_im[g];
        }
        __syncthreads();
        if (fl < F_) {
            #pragma unroll 4
            for (int t = 0; t < CT; ++t) {
                float br = ar_sh[t * AST + fl];
                float bi = ai_sh[t * AST + fl];
                #pragma unroll
                for (int k = 0; k < 4; ++k) {
                    float hr = hr_sh[(rg * 4 + k) * CT + t];
                    float hi = hi_sh[(rg * 4 + k) * CT + t];
                    hR[k] += hr * br; hR[k] -= hi * bi;
                    hI[k] += hr * bi; hI[k] += hi * br;
                }
            }
        }
    }
    if (fl < F_) {
        #pragma unroll
        for (int k = 0; k < 4; ++k) {
            int r = row0 + rg * 4 + k;
            int gi = r * F_ + fl;
            out[2 * gi]     = hR[k];
            out[2 * gi + 1] = hI[k];
        }
    }
}

extern "C" void kernel_launch(void* const* d_in, const int* in_sizes, int n_in,
                              void* d_out, int out_size, void* d_ws, size_t ws_size,
                              hipStream_t stream) {
    (void)in_sizes; (void)n_in; (void)out_size; (void)ws_size;
    const float* u  = (const float*)d_in[0];
    const float* Ar = (const float*)d_in[1];
    const float* Ai = (const float*)d_in[2];
    const float* th = (const float*)d_in[3];
    const float* Dr = (const float*)d_in[4];
    const float* Di = (const float*)d_in[5];
    float* out = (float*)d_out;

    float* ws = (float*)d_ws;
    float* z_re = ws;
    float* z_im = z_re + (size_t)B_ * F_;
    float* H_re = z_im + (size_t)B_ * F_;
    float* H_im = H_re + (size_t)B_ * T_;
    float* part_sig = H_im + (size_t)B_ * T_;   // NB_I entries
    float* part_dfr = part_sig + NB_I;          // NB_G entries
    float* part_dfi = part_dfr + NB_G;          // NB_G entries
    float* scal     = part_dfi + NB_G;          // [0]=sigma [1]=b_re [2]=b_im

    k_init<<<NB_I, 256, 0, stream>>>(u, z_re, z_im, H_re, H_im, part_sig);
    k_combine_sigma<<<1, 256, 0, stream>>>(part_sig, NB_I, scal);
    for (int l = 0; l < L_; ++l) {
        const float* Arl = Ar + (size_t)l * T_ * F_;
        const float* Ail = Ai + (size_t)l * T_ * F_;
        const float* thl = th + l * 3;
        k_forward<<<NB_G, 256, 0, stream>>>(z_re, z_im, H_re, H_im, Arl, Ail, thl, scal,
                                            part_dfr, part_dfi);
        k_combine_b<<<1, 256, 0, stream>>>(part_dfr, part_dfi, NB_G, thl, scal);
        k_backward<<<NB_G, 256, 0, stream>>>(z_re, z_im, H_re, H_im, Arl, Ail, u, scal, part_sig);
        if (l < L_ - 1)
            k_combine_sigma<<<1, 256, 0, stream>>>(part_sig, NB_G, scal);
    }
    k_final<<<NB_G, 256, 0, stream>>>(H_re, H_im, Dr, Di, out);
}

// Round 2
// 490.260 us; speedup vs baseline: 2.8587x; 2.8587x over previous
//
#include <hip/hip_runtime.h>
#include <hip/hip_bf16.h>
#include <math.h>

#define B_   8192
#define F_   48
#define T_   512
#define L_   8

typedef unsigned short ushort_t;
typedef unsigned int   uint_t;
typedef __attribute__((ext_vector_type(8))) short short8;
typedef __attribute__((ext_vector_type(4))) float f32x4;

#define MFMA(a,b,c) __builtin_amdgcn_mfma_f32_16x16x32_bf16(a,b,c,0,0,0)

__device__ inline ushort_t f2bf(float x) {
    __hip_bfloat16 h = __float2bfloat16(x);
    return *reinterpret_cast<ushort_t*>(&h);
}
__device__ inline float bf2f(ushort_t x) {
    __hip_bfloat16 h;
    *reinterpret_cast<ushort_t*>(&h) = x;
    return __bfloat162float(h);
}
__device__ inline short8 negbf(short8 v) {
    short8 r;
    #pragma unroll
    for (int i = 0; i < 8; ++i) r[i] = v[i] ^ (short)0x8000;
    return r;
}

// ---------------- prep: cast A / DFT to bf16 layouts ----------------
// Abr/Abi:  [L][512][64]  row-major, cols 48..63 zero   (forward B-frags)
// ATr/ATi:  [L][48][512]  transposed                    (backward B-frags)
// DTr/DTi:  [48][512]     transposed                    (final B-frags)
__global__ __launch_bounds__(256) void k_prep(
    const float* __restrict__ Ar, const float* __restrict__ Ai,
    const float* __restrict__ Dr, const float* __restrict__ Di,
    ushort_t* __restrict__ Abr, ushort_t* __restrict__ Abi,
    ushort_t* __restrict__ ATr, ushort_t* __restrict__ ATi,
    ushort_t* __restrict__ DTr, ushort_t* __restrict__ DTi)
{
    const int gt = blockIdx.x * 256 + threadIdx.x;
    const int gs = gridDim.x * 256;
    for (int idx = gt; idx < L_ * 512 * 64; idx += gs) {
        int l = idx >> 15;
        int rem = idx & 32767;
        int t = rem >> 6, c = rem & 63;
        float vr = 0.f, vi = 0.f;
        if (c < 48) { int g = l * 24576 + t * 48 + c; vr = Ar[g]; vi = Ai[g]; }
        Abr[idx] = f2bf(vr); Abi[idx] = f2bf(vi);
    }
    for (int idx = gt; idx < L_ * 48 * 512; idx += gs) {
        int l = idx / 24576;
        int rem = idx - l * 24576;
        int f = rem >> 9, t = rem & 511;
        int g = l * 24576 + t * 48 + f;
        ATr[idx] = f2bf(Ar[g]); ATi[idx] = f2bf(Ai[g]);
    }
    for (int idx = gt; idx < 48 * 512; idx += gs) {
        int f = idx >> 9, t = idx & 511;
        DTr[idx] = f2bf(Dr[t * 48 + f]); DTi[idx] = f2bf(Di[t * 48 + f]);
    }
}

// ---------------- init: z = u, Hb = 0, partial ||z||^2 ----------------
__global__ __launch_bounds__(256) void k_init(
    const float* __restrict__ u, float* __restrict__ z_re, float* __restrict__ z_im,
    uint_t* __restrict__ Hre_u, uint_t* __restrict__ Him_u, float* __restrict__ part)
{
    __shared__ float red[256];
    const int tid = threadIdx.x;
    const int gt = blockIdx.x * 256 + tid;
    const int gs = gridDim.x * 256;
    float acc = 0.f;
    for (int i = gt; i < B_ * F_; i += gs) {
        float ur = u[2 * i], ui = u[2 * i + 1];
        z_re[i] = ur; z_im[i] = ui;
        acc += ur * ur + ui * ui;
    }
    const int nHu = B_ * T_ / 2;   // uints per plane
    for (int i = gt; i < nHu; i += gs) { Hre_u[i] = 0u; Him_u[i] = 0u; }
    red[tid] = acc; __syncthreads();
    for (int s = 128; s > 0; s >>= 1) { if (tid < s) red[tid] += red[tid + s]; __syncthreads(); }
    if (tid == 0) part[blockIdx.x] = red[0];
}

// ---------------- combine sigma ----------------
__global__ __launch_bounds__(256) void k_combine_sigma(
    const float* __restrict__ part, int n, float* __restrict__ scal)
{
    __shared__ float red[256];
    const int tid = threadIdx.x;
    float s = 0.f;
    for (int i = tid; i < n; i += 256) s += part[i];
    red[tid] = s; __syncthreads();
    for (int st = 128; st > 0; st >>= 1) { if (tid < st) red[tid] += red[tid + st]; __syncthreads(); }
    if (tid == 0) scal[0] = sqrtf(red[0]) / sqrtf(48.0f);
}

// ---------------- combine b ----------------
__global__ __launch_bounds__(256) void k_combine_b(
    const float* __restrict__ pr, const float* __restrict__ pi, int n,
    const float* __restrict__ th, float* __restrict__ scal)
{
    __shared__ float red[256];
    const int tid = threadIdx.x;
    float sr = 0.f, si = 0.f;
    for (int i = tid; i < n; i += 256) { sr += pr[i]; si += pi[i]; }
    red[tid] = sr; __syncthreads();
    for (int st = 128; st > 0; st >>= 1) { if (tid < st) red[tid] += red[tid + st]; __syncthreads(); }
    float tr = red[0]; __syncthreads();
    red[tid] = si; __syncthreads();
    for (int st = 128; st > 0; st >>= 1) { if (tid < st) red[tid] += red[tid + st]; __syncthreads(); }
    if (tid == 0) {
        float th1 = th[1];
        scal[1] = th1 * tr / 48.0f;
        scal[2] = th1 * red[0] / 48.0f;
    }
}

// ---------------- forward: Z = z@A^T (MFMA), R = Hold + Z, act -> Hnew, count partials ----
// grid 512 blocks; block = 16 rows x 512 cols; wave w covers cols [w*128, w*128+128)
__global__ __launch_bounds__(256) void k_forward(
    const float* __restrict__ z_re, const float* __restrict__ z_im,
    ushort_t* __restrict__ Hre, ushort_t* __restrict__ Him,
    const ushort_t* __restrict__ Abr, const ushort_t* __restrict__ Abi,
    const float* __restrict__ th, const float* __restrict__ scal,
    float* __restrict__ part_r, float* __restrict__ part_i)
{
    __shared__ __align__(16) ushort_t zshr[16 * 72];
    __shared__ __align__(16) ushort_t zshi[16 * 72];
    __shared__ float red[256];
    const int tid = threadIdx.x;
    const int row0 = blockIdx.x * 16;
    // stage z rows (fp32 -> bf16), cols 48..63 zero (K padding)
    for (int idx = tid; idx < 16 * 64; idx += 256) {
        int r = idx >> 6, c = idx & 63;
        float vr = 0.f, vi = 0.f;
        if (c < 48) { int g = (row0 + r) * 48 + c; vr = z_re[g]; vi = z_im[g]; }
        zshr[r * 72 + c] = f2bf(vr);
        zshi[r * 72 + c] = f2bf(vi);
    }
    __syncthreads();
    const int wave = tid >> 6, lane = tid & 63;
    const int quad = lane >> 4, m = lane & 15;
    const int wcol0 = wave * 128;
    // A-operand frags: A[m=lane&15][k=quad*8+j]
    short8 zr0 = *(const short8*)&zshr[m * 72 + quad * 8];
    short8 zr1 = *(const short8*)&zshr[m * 72 + 32 + quad * 8];
    short8 zi0 = *(const short8*)&zshi[m * 72 + quad * 8];
    short8 zi1 = *(const short8*)&zshi[m * 72 + 32 + quad * 8];
    short8 zin0 = negbf(zi0), zin1 = negbf(zi1);
    const float lam = th[0] * scal[0];
    const float th1 = th[1];
    float cr = 0.f, ci = 0.f;
    for (int ct = 0; ct < 8; ++ct) {
        const int t0 = wcol0 + ct * 16;
        // B-operand frags: B[k=quad*8+j][n=lane&15] = A[t0+n][k]
        const ushort_t* ar_p = Abr + (size_t)(t0 + m) * 64 + quad * 8;
        const ushort_t* ai_p = Abi + (size_t)(t0 + m) * 64 + quad * 8;
        short8 ar0 = *(const short8*)ar_p;
        short8 ar1 = *(const short8*)(ar_p + 32);
        short8 ai0 = *(const short8*)ai_p;
        short8 ai1 = *(const short8*)(ai_p + 32);
        f32x4 accR = {0.f, 0.f, 0.f, 0.f};
        f32x4 accI = {0.f, 0.f, 0.f, 0.f};
        accR = MFMA(zr0, ar0, accR);
        accR = MFMA(zr1, ar1, accR);
        accR = MFMA(zin0, ai0, accR);
        accR = MFMA(zin1, ai1, accR);
        accI = MFMA(zr0, ai0, accI);
        accI = MFMA(zr1, ai1, accI);
        accI = MFMA(zi0, ar0, accI);
        accI = MFMA(zi1, ar1, accI);
        // C/D: col = lane&15, row = quad*4 + reg
        const int t = t0 + m;
        #pragma unroll
        for (int reg = 0; reg < 4; ++reg) {
            const int r = row0 + quad * 4 + reg;
            const size_t gi = (size_t)r * 512 + t;
            float Rr = bf2f(Hre[gi]) + accR[reg];
            float Ri = bf2f(Him[gi]) + accI[reg];
            float mr = fabsf(Rr), mi = fabsf(Ri);
            float fr = th1 * copysignf(fmaxf(mr - lam, 0.f), Rr);
            float fi = th1 * copysignf(fmaxf(mi - lam, 0.f), Ri);
            cr += (mr > lam) ? 1.f : 0.f;
            ci += (mi > lam) ? 1.f : 0.f;
            Hre[gi] = f2bf(fr);
            Him[gi] = f2bf(fi);
        }
    }
    red[tid] = cr; __syncthreads();
    for (int s = 128; s > 0; s >>= 1) { if (tid < s) red[tid] += red[tid + s]; __syncthreads(); }
    if (tid == 0) part_r[blockIdx.x] = red[0];
    __syncthreads();
    red[tid] = ci; __syncthreads();
    for (int s = 128; s > 0; s >>= 1) { if (tid < s) red[tid] += red[tid + s]; __syncthreads(); }
    if (tid == 0) part_i[blockIdx.x] = red[0];
}

// ---------------- backward: h = H@A (MFMA), zn = u - h + b*z, partial ||zn||^2 ----
// grid 128 blocks; wave w owns rows [blk*64 + w*16, +16)
__global__ __launch_bounds__(256) void k_backward(
    float* __restrict__ z_re, float* __restrict__ z_im,
    const ushort_t* __restrict__ Hre, const ushort_t* __restrict__ Him,
    const ushort_t* __restrict__ ATr, const ushort_t* __restrict__ ATi,
    const float* __restrict__ u, const float* __restrict__ scal,
    float* __restrict__ part)
{
    __shared__ float red[256];
    const int tid = threadIdx.x;
    const int wave = tid >> 6, lane = tid & 63;
    const int quad = lane >> 4, m = lane & 15;
    const int wrow0 = blockIdx.x * 64 + wave * 16;
    f32x4 aR[3], aI[3];
    #pragma unroll
    for (int ft = 0; ft < 3; ++ft) {
        aR[ft] = (f32x4){0.f, 0.f, 0.f, 0.f};
        aI[ft] = (f32x4){0.f, 0.f, 0.f, 0.f};
    }
    const ushort_t* hbr = Hre + (size_t)(wrow0 + m) * 512;
    const ushort_t* hbi = Him + (size_t)(wrow0 + m) * 512;
    for (int ks = 0; ks < 16; ++ks) {
        const int k0 = ks * 32 + quad * 8;
        short8 hr = *(const short8*)(hbr + k0);
        short8 hi = *(const short8*)(hbi + k0);
        short8 hin = negbf(hi);
        #pragma unroll
        for (int ft = 0; ft < 3; ++ft) {
            const ushort_t* brp = ATr + (size_t)(ft * 16 + m) * 512 + k0;
            const ushort_t* bip = ATi + (size_t)(ft * 16 + m) * 512 + k0;
            short8 br = *(const short8*)brp;
            short8 bi = *(const short8*)bip;
            aR[ft] = MFMA(hr, br, aR[ft]);
            aR[ft] = MFMA(hin, bi, aR[ft]);
            aI[ft] = MFMA(hr, bi, aI[ft]);
            aI[ft] = MFMA(hi, br, aI[ft]);
        }
    }
    const float bs_r = scal[1], bs_i = scal[2];
    float nrm = 0.f;
    #pragma unroll
    for (int ft = 0; ft < 3; ++ft) {
        const int f = ft * 16 + m;
        #pragma unroll
        for (int reg = 0; reg < 4; ++reg) {
            const int r = wrow0 + quad * 4 + reg;
            const int gi = r * 48 + f;
            float zr = z_re[gi], zi = z_im[gi];
            float znr = u[2 * gi]     - aR[ft][reg] + bs_r * zr;
            float zni = u[2 * gi + 1] - aI[ft][reg] + bs_i * zi;
            z_re[gi] = znr; z_im[gi] = zni;
            nrm += znr * znr + zni * zni;
        }
    }
    red[tid] = nrm; __syncthreads();
    for (int s = 128; s > 0; s >>= 1) { if (tid < s) red[tid] += red[tid + s]; __syncthreads(); }
    if (tid == 0) part[blockIdx.x] = red[0];
}

// ---------------- final: out = stack(H @ DFT) via MFMA ----------------
__global__ __launch_bounds__(256) void k_final(
    const ushort_t* __restrict__ Hre, const ushort_t* __restrict__ Him,
    const ushort_t* __restrict__ DTr, const ushort_t* __restrict__ DTi,
    float* __restrict__ out)
{
    const int tid = threadIdx.x;
    const int wave = tid >> 6, lane = tid & 63;
    const int quad = lane >> 4, m = lane & 15;
    const int wrow0 = blockIdx.x * 64 + wave * 16;
    f32x4 aR[3], aI[3];
    #pragma unroll
    for (int ft = 0; ft < 3; ++ft) {
        aR[ft] = (f32x4){0.f, 0.f, 0.f, 0.f};
        aI[ft] = (f32x4){0.f, 0.f, 0.f, 0.f};
    }
    const ushort_t* hbr = Hre + (size_t)(wrow0 + m) * 512;
    const ushort_t* hbi = Him + (size_t)(wrow0 + m) * 512;
    for (int ks = 0; ks < 16; ++ks) {
        const int k0 = ks * 32 + quad * 8;
        short8 hr = *(const short8*)(hbr + k0);
        short8 hi = *(const short8*)(hbi + k0);
        short8 hin = negbf(hi);
        #pragma unroll
        for (int ft = 0; ft < 3; ++ft) {
            const ushort_t* brp = DTr + (size_t)(ft * 16 + m) * 512 + k0;
            const ushort_t* bip = DTi + (size_t)(ft * 16 + m) * 512 + k0;
            short8 br = *(const short8*)brp;
            short8 bi = *(const short8*)bip;
            aR[ft] = MFMA(hr, br, aR[ft]);
            aR[ft] = MFMA(hin, bi, aR[ft]);
            aI[ft] = MFMA(hr, bi, aI[ft]);
            aI[ft] = MFMA(hi, br, aI[ft]);
        }
    }
    #pragma unroll
    for (int ft = 0; ft < 3; ++ft) {
        const int f = ft * 16 + m;
        #pragma unroll
        for (int reg = 0; reg < 4; ++reg) {
            const int r = wrow0 + quad * 4 + reg;
            const int gi = r * 48 + f;
            out[2 * gi]     = aR[ft][reg];
            out[2 * gi + 1] = aI[ft][reg];
        }
    }
}

extern "C" void kernel_launch(void* const* d_in, const int* in_sizes, int n_in,
                              void* d_out, int out_size, void* d_ws, size_t ws_size,
                              hipStream_t stream) {
    (void)in_sizes; (void)n_in; (void)out_size; (void)ws_size;
    const float* u  = (const float*)d_in[0];
    const float* Ar = (const float*)d_in[1];
    const float* Ai = (const float*)d_in[2];
    const float* th = (const float*)d_in[3];
    const float* Dr = (const float*)d_in[4];
    const float* Di = (const float*)d_in[5];
    float* out = (float*)d_out;

    char* p = (char*)d_ws;
    auto alloc = [&](size_t bytes) -> char* {
        char* r = p;
        p += (bytes + 63) & ~(size_t)63;
        return r;
    };
    float* z_re   = (float*)alloc((size_t)B_ * F_ * 4);
    float* z_im   = (float*)alloc((size_t)B_ * F_ * 4);
    float* part_a = (float*)alloc(512 * 4);   // sigma partials (max 512 blocks)
    float* part_br= (float*)alloc(512 * 4);
    float* part_bi= (float*)alloc(512 * 4);
    float* scal   = (float*)alloc(16 * 4);    // [0]=sigma [1]=b_re [2]=b_im
    ushort_t* Hre = (ushort_t*)alloc((size_t)B_ * T_ * 2);
    ushort_t* Him = (ushort_t*)alloc((size_t)B_ * T_ * 2);
    ushort_t* Abr = (ushort_t*)alloc((size_t)L_ * 512 * 64 * 2);
    ushort_t* Abi = (ushort_t*)alloc((size_t)L_ * 512 * 64 * 2);
    ushort_t* ATr = (ushort_t*)alloc((size_t)L_ * 48 * 512 * 2);
    ushort_t* ATi = (ushort_t*)alloc((size_t)L_ * 48 * 512 * 2);
    ushort_t* DTr = (ushort_t*)alloc((size_t)48 * 512 * 2);
    ushort_t* DTi = (ushort_t*)alloc((size_t)48 * 512 * 2);

    k_prep<<<256, 256, 0, stream>>>(Ar, Ai, Dr, Di, Abr, Abi, ATr, ATi, DTr, DTi);
    k_init<<<256, 256, 0, stream>>>(u, z_re, z_im, (uint_t*)Hre, (uint_t*)Him, part_a);
    k_combine_sigma<<<1, 256, 0, stream>>>(part_a, 256, scal);
    for (int l = 0; l < L_; ++l) {
        const ushort_t* Abrl = Abr + (size_t)l * 512 * 64;
        const ushort_t* Abil = Abi + (size_t)l * 512 * 64;
        const ushort_t* ATrl = ATr + (size_t)l * 48 * 512;
        const ushort_t* ATil = ATi + (size_t)l * 48 * 512;
        const float* thl = th + l * 3;
        k_forward<<<512, 256, 0, stream>>>(z_re, z_im, Hre, Him, Abrl, Abil, thl, scal,
                                           part_br, part_bi);
        k_combine_b<<<1, 256, 0, stream>>>(part_br, part_bi, 512, thl, scal);
        k_backward<<<128, 256, 0, stream>>>(z_re, z_im, Hre, Him, ATrl, ATil, u, scal, part_a);
        if (l < L_ - 1)
            k_combine_sigma<<<1, 256, 0, stream>>>(part_a, 128, scal);
    }
    k_final<<<128, 256, 0, stream>>>(Hre, Him, DTr, DTi, out);
}

// Round 3
// 410.771 us; speedup vs baseline: 3.4119x; 1.1935x over previous
//
#include <hip/hip_runtime.h>
#include <hip/hip_bf16.h>
#include <math.h>

#define B_   8192
#define F_   48
#define T_   512
#define L_   8

typedef unsigned short ushort_t;
typedef unsigned int   uint_t;
typedef __attribute__((ext_vector_type(8))) short short8;
typedef __attribute__((ext_vector_type(4))) float f32x4;

#define MFMA(a,b,c) __builtin_amdgcn_mfma_f32_16x16x32_bf16(a,b,c,0,0,0)

__device__ inline ushort_t f2bf(float x) {
    __hip_bfloat16 h = __float2bfloat16(x);
    return *reinterpret_cast<ushort_t*>(&h);
}
__device__ inline float bf2f(ushort_t x) {
    __hip_bfloat16 h;
    *reinterpret_cast<ushort_t*>(&h) = x;
    return __bfloat162float(h);
}
__device__ inline short8 negbf(short8 v) {
    short8 r;
    #pragma unroll
    for (int i = 0; i < 8; ++i) r[i] = v[i] ^ (short)0x8000;
    return r;
}

// ---------- prep + init: bf16 A layouts, z = u, sigma partials ----------
// Abr/Abi:[L][512][64] (fwd B-frags, cols 48..63 zero); ATr/ATi:[L][48][512];
// DTr/DTi:[48][512]. part_sig[256].
__global__ __launch_bounds__(256) void k_prep_init(
    const float* __restrict__ u,
    const float* __restrict__ Ar, const float* __restrict__ Ai,
    const float* __restrict__ Dr, const float* __restrict__ Di,
    float* __restrict__ z_re, float* __restrict__ z_im,
    ushort_t* __restrict__ Abr, ushort_t* __restrict__ Abi,
    ushort_t* __restrict__ ATr, ushort_t* __restrict__ ATi,
    ushort_t* __restrict__ DTr, ushort_t* __restrict__ DTi,
    float* __restrict__ part_sig)
{
    __shared__ float red[256];
    const int tid = threadIdx.x;
    const int gt = blockIdx.x * 256 + tid;
    const int gs = gridDim.x * 256;
    for (int idx = gt; idx < L_ * 512 * 64; idx += gs) {
        int l = idx >> 15, rem = idx & 32767;
        int t = rem >> 6, c = rem & 63;
        float vr = 0.f, vi = 0.f;
        if (c < 48) { int g = l * 24576 + t * 48 + c; vr = Ar[g]; vi = Ai[g]; }
        Abr[idx] = f2bf(vr); Abi[idx] = f2bf(vi);
    }
    for (int idx = gt; idx < L_ * 48 * 512; idx += gs) {
        int l = idx / 24576, rem = idx - l * 24576;
        int f = rem >> 9, t = rem & 511;
        int g = l * 24576 + t * 48 + f;
        ATr[idx] = f2bf(Ar[g]); ATi[idx] = f2bf(Ai[g]);
    }
    for (int idx = gt; idx < 48 * 512; idx += gs) {
        int f = idx >> 9, t = idx & 511;
        DTr[idx] = f2bf(Dr[t * 48 + f]); DTi[idx] = f2bf(Di[t * 48 + f]);
    }
    float acc = 0.f;
    for (int i = gt; i < B_ * F_; i += gs) {
        float ur = u[2 * i], ui = u[2 * i + 1];
        z_re[i] = ur; z_im[i] = ui;
        acc += ur * ur + ui * ui;
    }
    red[tid] = acc; __syncthreads();
    for (int s = 128; s > 0; s >>= 1) { if (tid < s) red[tid] += red[tid + s]; __syncthreads(); }
    if (tid == 0) part_sig[blockIdx.x] = red[0];
}

// ---------- forward: sigma-combine + Z = z@A^T + act -> Hn; FINAL fuses Hn@DFT ----------
// grid 512 blocks x 256 thr; block = 16 rows x 512 cols; wave w = cols [w*128,+128)
template<bool FIRST, bool FINAL>
__global__ __launch_bounds__(256) void k_fwd(
    const float* __restrict__ z_re, const float* __restrict__ z_im,
    ushort_t* __restrict__ Hre, ushort_t* __restrict__ Him,
    const ushort_t* __restrict__ Abr, const ushort_t* __restrict__ Abi,
    const ushort_t* __restrict__ DTr, const ushort_t* __restrict__ DTi,
    const float* __restrict__ th, const float* __restrict__ part_sig,
    float* __restrict__ part_r, float* __restrict__ part_i,
    float* __restrict__ out)
{
    __shared__ float red[256];
    __shared__ __align__(16) ushort_t zshr[16 * 72];
    __shared__ __align__(16) ushort_t zshi[16 * 72];
    extern __shared__ __align__(16) char dynbuf[];   // FINAL only: hn(33280) + pR/pI(24576)
    ushort_t* hnr = (ushort_t*)dynbuf;               // [16*520]
    ushort_t* hni = hnr + 16 * 520;
    float* pR = (float*)(dynbuf + 16 * 520 * 2 * 2); // [4][3][16][16]
    float* pI = pR + 4 * 3 * 16 * 16;

    const int tid = threadIdx.x;
    // fused sigma combine (part_sig has 256 entries)
    red[tid] = part_sig[tid]; __syncthreads();
    for (int s = 128; s > 0; s >>= 1) { if (tid < s) red[tid] += red[tid + s]; __syncthreads(); }
    const float lam = th[0] * sqrtf(red[0] * (1.0f / 48.0f));
    const float th1 = th[1];

    const int row0 = blockIdx.x * 16;
    for (int idx = tid; idx < 16 * 64; idx += 256) {
        int r = idx >> 6, c = idx & 63;
        float vr = 0.f, vi = 0.f;
        if (c < 48) { int g = (row0 + r) * 48 + c; vr = z_re[g]; vi = z_im[g]; }
        zshr[r * 72 + c] = f2bf(vr);
        zshi[r * 72 + c] = f2bf(vi);
    }
    __syncthreads();
    const int wave = tid >> 6, lane = tid & 63;
    const int quad = lane >> 4, m = lane & 15;
    const int wcol0 = wave * 128;
    short8 zr0 = *(const short8*)&zshr[m * 72 + quad * 8];
    short8 zr1 = *(const short8*)&zshr[m * 72 + 32 + quad * 8];
    short8 zi0 = *(const short8*)&zshi[m * 72 + quad * 8];
    short8 zi1 = *(const short8*)&zshi[m * 72 + 32 + quad * 8];
    short8 zin0 = negbf(zi0), zin1 = negbf(zi1);
    float cr = 0.f, ci = 0.f;
    for (int ct = 0; ct < 8; ++ct) {
        const int t0 = wcol0 + ct * 16;
        const ushort_t* ar_p = Abr + (size_t)(t0 + m) * 64 + quad * 8;
        const ushort_t* ai_p = Abi + (size_t)(t0 + m) * 64 + quad * 8;
        short8 ar0 = *(const short8*)ar_p;
        short8 ar1 = *(const short8*)(ar_p + 32);
        short8 ai0 = *(const short8*)ai_p;
        short8 ai1 = *(const short8*)(ai_p + 32);
        f32x4 accR = {0.f, 0.f, 0.f, 0.f};
        f32x4 accI = {0.f, 0.f, 0.f, 0.f};
        accR = MFMA(zr0, ar0, accR);
        accR = MFMA(zr1, ar1, accR);
        accR = MFMA(zin0, ai0, accR);
        accR = MFMA(zin1, ai1, accR);
        accI = MFMA(zr0, ai0, accI);
        accI = MFMA(zr1, ai1, accI);
        accI = MFMA(zi0, ar0, accI);
        accI = MFMA(zi1, ar1, accI);
        const int t = t0 + m;
        #pragma unroll
        for (int reg = 0; reg < 4; ++reg) {
            const int lr = quad * 4 + reg;
            const int r = row0 + lr;
            const size_t gi = (size_t)r * 512 + t;
            float Rr = accR[reg], Ri = accI[reg];
            if constexpr (!FIRST) { Rr += bf2f(Hre[gi]); Ri += bf2f(Him[gi]); }
            float mr = fabsf(Rr), mi = fabsf(Ri);
            float fr = th1 * copysignf(fmaxf(mr - lam, 0.f), Rr);
            float fi = th1 * copysignf(fmaxf(mi - lam, 0.f), Ri);
            if constexpr (!FINAL) {
                cr += (mr > lam) ? 1.f : 0.f;
                ci += (mi > lam) ? 1.f : 0.f;
                Hre[gi] = f2bf(fr);
                Him[gi] = f2bf(fi);
            } else {
                hnr[lr * 520 + t] = f2bf(fr);
                hni[lr * 520 + t] = f2bf(fi);
            }
        }
    }
    if constexpr (!FINAL) {
        __syncthreads();
        red[tid] = cr; __syncthreads();
        for (int s = 128; s > 0; s >>= 1) { if (tid < s) red[tid] += red[tid + s]; __syncthreads(); }
        if (tid == 0) part_r[blockIdx.x] = red[0];
        __syncthreads();
        red[tid] = ci; __syncthreads();
        for (int s = 128; s > 0; s >>= 1) { if (tid < s) red[tid] += red[tid + s]; __syncthreads(); }
        if (tid == 0) part_i[blockIdx.x] = red[0];
    } else {
        __syncthreads();
        // final GEMM: out(16 x 48 complex) = Hn(16x512) @ DFT(512x48), K split across waves
        f32x4 fR[3], fI[3];
        #pragma unroll
        for (int ft = 0; ft < 3; ++ft) { fR[ft] = (f32x4){0,0,0,0}; fI[ft] = (f32x4){0,0,0,0}; }
        for (int ks = 0; ks < 4; ++ks) {
            const int k0 = wave * 128 + ks * 32 + quad * 8;
            short8 hr = *(const short8*)&hnr[m * 520 + k0];
            short8 hi = *(const short8*)&hni[m * 520 + k0];
            short8 hin = negbf(hi);
            #pragma unroll
            for (int ft = 0; ft < 3; ++ft) {
                short8 br = *(const short8*)(DTr + (size_t)(ft * 16 + m) * 512 + k0);
                short8 bi = *(const short8*)(DTi + (size_t)(ft * 16 + m) * 512 + k0);
                fR[ft] = MFMA(hr, br, fR[ft]);
                fR[ft] = MFMA(hin, bi, fR[ft]);
                fI[ft] = MFMA(hr, bi, fI[ft]);
                fI[ft] = MFMA(hi, br, fI[ft]);
            }
        }
        #pragma unroll
        for (int ft = 0; ft < 3; ++ft) {
            #pragma unroll
            for (int reg = 0; reg < 4; ++reg) {
                const int lr = quad * 4 + reg;
                pR[((wave * 3 + ft) * 16 + lr) * 16 + m] = fR[ft][reg];
                pI[((wave * 3 + ft) * 16 + lr) * 16 + m] = fI[ft][reg];
            }
        }
        __syncthreads();
        #pragma unroll
        for (int k = 0; k < 3; ++k) {
            const int o = tid + k * 256;
            const int ft = o >> 8, rem = o & 255;
            const int r = rem >> 4, c = rem & 15;
            float sre = 0.f, sim = 0.f;
            #pragma unroll
            for (int w = 0; w < 4; ++w) {
                sre += pR[((w * 3 + ft) * 16 + r) * 16 + c];
                sim += pI[((w * 3 + ft) * 16 + r) * 16 + c];
            }
            const int gi = (row0 + r) * 48 + ft * 16 + c;
            out[2 * gi]     = sre;
            out[2 * gi + 1] = sim;
        }
    }
}

// ---------- backward: b-combine + h = H@A, zn = u - h + b*z, sigma partials ----------
// grid 256 blocks x 128 thr; wave w owns rows [blk*32 + w*16, +16)
__global__ __launch_bounds__(128) void k_bwd(
    float* __restrict__ z_re, float* __restrict__ z_im,
    const ushort_t* __restrict__ Hre, const ushort_t* __restrict__ Him,
    const ushort_t* __restrict__ ATr, const ushort_t* __restrict__ ATi,
    const float* __restrict__ u, const float* __restrict__ th,
    const float* __restrict__ part_r, const float* __restrict__ part_i,
    float* __restrict__ part_sig)
{
    __shared__ float red[128];
    const int tid = threadIdx.x;
    // fused b combine (512 partials)
    float sr = part_r[tid] + part_r[tid + 128] + part_r[tid + 256] + part_r[tid + 384];
    red[tid] = sr; __syncthreads();
    for (int s = 64; s > 0; s >>= 1) { if (tid < s) red[tid] += red[tid + s]; __syncthreads(); }
    const float bre = th[1] * red[0] * (1.0f / 48.0f);
    __syncthreads();
    float si = part_i[tid] + part_i[tid + 128] + part_i[tid + 256] + part_i[tid + 384];
    red[tid] = si; __syncthreads();
    for (int s = 64; s > 0; s >>= 1) { if (tid < s) red[tid] += red[tid + s]; __syncthreads(); }
    const float bim = th[1] * red[0] * (1.0f / 48.0f);

    const int wave = tid >> 6, lane = tid & 63;
    const int quad = lane >> 4, m = lane & 15;
    const int wrow0 = blockIdx.x * 32 + wave * 16;
    f32x4 aR[3], aI[3];
    #pragma unroll
    for (int ft = 0; ft < 3; ++ft) { aR[ft] = (f32x4){0,0,0,0}; aI[ft] = (f32x4){0,0,0,0}; }
    const ushort_t* hbr = Hre + (size_t)(wrow0 + m) * 512;
    const ushort_t* hbi = Him + (size_t)(wrow0 + m) * 512;
    for (int ks = 0; ks < 16; ++ks) {
        const int k0 = ks * 32 + quad * 8;
        short8 hr = *(const short8*)(hbr + k0);
        short8 hi = *(const short8*)(hbi + k0);
        short8 hin = negbf(hi);
        #pragma unroll
        for (int ft = 0; ft < 3; ++ft) {
            short8 br = *(const short8*)(ATr + (size_t)(ft * 16 + m) * 512 + k0);
            short8 bi = *(const short8*)(ATi + (size_t)(ft * 16 + m) * 512 + k0);
            aR[ft] = MFMA(hr, br, aR[ft]);
            aR[ft] = MFMA(hin, bi, aR[ft]);
            aI[ft] = MFMA(hr, bi, aI[ft]);
            aI[ft] = MFMA(hi, br, aI[ft]);
        }
    }
    const float2* u2 = (const float2*)u;
    float nrm = 0.f;
    #pragma unroll
    for (int ft = 0; ft < 3; ++ft) {
        const int f = ft * 16 + m;
        #pragma unroll
        for (int reg = 0; reg < 4; ++reg) {
            const int r = wrow0 + quad * 4 + reg;
            const int gi = r * 48 + f;
            float zr = z_re[gi], zi = z_im[gi];
            float2 uv = u2[gi];
            float znr = uv.x - aR[ft][reg] + bre * zr;
            float zni = uv.y - aI[ft][reg] + bim * zi;
            z_re[gi] = znr; z_im[gi] = zni;
            nrm += znr * znr + zni * zni;
        }
    }
    __syncthreads();
    red[tid] = nrm; __syncthreads();
    for (int s = 64; s > 0; s >>= 1) { if (tid < s) red[tid] += red[tid + s]; __syncthreads(); }
    if (tid == 0) part_sig[blockIdx.x] = red[0];
}

extern "C" void kernel_launch(void* const* d_in, const int* in_sizes, int n_in,
                              void* d_out, int out_size, void* d_ws, size_t ws_size,
                              hipStream_t stream) {
    (void)in_sizes; (void)n_in; (void)out_size; (void)ws_size;
    const float* u  = (const float*)d_in[0];
    const float* Ar = (const float*)d_in[1];
    const float* Ai = (const float*)d_in[2];
    const float* th = (const float*)d_in[3];
    const float* Dr = (const float*)d_in[4];
    const float* Di = (const float*)d_in[5];
    float* out = (float*)d_out;

    char* p = (char*)d_ws;
    auto alloc = [&](size_t bytes) -> char* {
        char* r = p;
        p += (bytes + 255) & ~(size_t)255;
        return r;
    };
    float* z_re    = (float*)alloc((size_t)B_ * F_ * 4);
    float* z_im    = (float*)alloc((size_t)B_ * F_ * 4);
    float* part_sig= (float*)alloc(256 * 4);
    float* part_r  = (float*)alloc(512 * 4);
    float* part_i  = (float*)alloc(512 * 4);
    ushort_t* Hre  = (ushort_t*)alloc((size_t)B_ * T_ * 2);
    ushort_t* Him  = (ushort_t*)alloc((size_t)B_ * T_ * 2);
    ushort_t* Abr  = (ushort_t*)alloc((size_t)L_ * 512 * 64 * 2);
    ushort_t* Abi  = (ushort_t*)alloc((size_t)L_ * 512 * 64 * 2);
    ushort_t* ATr  = (ushort_t*)alloc((size_t)L_ * 48 * 512 * 2);
    ushort_t* ATi  = (ushort_t*)alloc((size_t)L_ * 48 * 512 * 2);
    ushort_t* DTr  = (ushort_t*)alloc((size_t)48 * 512 * 2);
    ushort_t* DTi  = (ushort_t*)alloc((size_t)48 * 512 * 2);

    k_prep_init<<<256, 256, 0, stream>>>(u, Ar, Ai, Dr, Di, z_re, z_im,
                                         Abr, Abi, ATr, ATi, DTr, DTi, part_sig);
    for (int l = 0; l < L_; ++l) {
        const ushort_t* Abrl = Abr + (size_t)l * 512 * 64;
        const ushort_t* Abil = Abi + (size_t)l * 512 * 64;
        const float* thl = th + l * 3;
        if (l == 0) {
            k_fwd<true, false><<<512, 256, 0, stream>>>(z_re, z_im, Hre, Him, Abrl, Abil,
                DTr, DTi, thl, part_sig, part_r, part_i, out);
        } else if (l < L_ - 1) {
            k_fwd<false, false><<<512, 256, 0, stream>>>(z_re, z_im, Hre, Him, Abrl, Abil,
                DTr, DTi, thl, part_sig, part_r, part_i, out);
        } else {
            // last layer: fused final GEMM, no H write, no b partials
            k_fwd<false, true><<<512, 256, 57856, stream>>>(z_re, z_im, Hre, Him, Abrl, Abil,
                DTr, DTi, thl, part_sig, part_r, part_i, out);
            break;
        }
        const ushort_t* ATrl = ATr + (size_t)l * 48 * 512;
        const ushort_t* ATil = ATi + (size_t)l * 48 * 512;
        k_bwd<<<256, 128, 0, stream>>>(z_re, z_im, Hre, Him, ATrl, ATil, u, thl,
                                       part_r, part_i, part_sig);
    }
}

// Round 4
// 361.328 us; speedup vs baseline: 3.8787x; 1.1368x over previous
//
#include <hip/hip_runtime.h>
#include <hip/hip_bf16.h>
#include <math.h>

#define B_   8192
#define F_   48
#define T_   512
#define L_   8
#define NBLK 256
#define RPB  32          // rows per block (B_/NBLK)
#define HST  520         // H LDS row stride in shorts (1040B: 16B-mult, b128 reads ~2-way)
#define ZS   52          // z LDS row stride in floats (208B: 16B-mult, 2-way free)

typedef unsigned short ushort_t;
typedef unsigned int   uint_t;
typedef __attribute__((ext_vector_type(8))) short short8;
typedef __attribute__((ext_vector_type(4))) float f32x4;

#define MFMA(a,b,c) __builtin_amdgcn_mfma_f32_16x16x32_bf16(a,b,c,0,0,0)

__device__ inline ushort_t f2bf(float x) {
    __hip_bfloat16 h = __float2bfloat16(x);
    return *reinterpret_cast<ushort_t*>(&h);
}
__device__ inline float bf2f(ushort_t x) {
    __hip_bfloat16 h;
    *reinterpret_cast<ushort_t*>(&h) = x;
    return __bfloat162float(h);
}
__device__ inline short8 negbf(short8 v) {
    short8 r;
    #pragma unroll
    for (int i = 0; i < 8; ++i) r[i] = v[i] ^ (short)0x8000;
    return r;
}
__device__ inline short8 pack8(float4 a, float4 b) {
    short8 r;
    r[0]=(short)f2bf(a.x); r[1]=(short)f2bf(a.y); r[2]=(short)f2bf(a.z); r[3]=(short)f2bf(a.w);
    r[4]=(short)f2bf(b.x); r[5]=(short)f2bf(b.y); r[6]=(short)f2bf(b.z); r[7]=(short)f2bf(b.w);
    return r;
}

__device__ inline float blk_reduce(float v, float* red) {
    const int tid = threadIdx.x;
    __syncthreads();           // protect any prior use of red
    red[tid] = v; __syncthreads();
    #pragma unroll
    for (int s = 128; s > 0; s >>= 1) {
        if (tid < s) red[tid] += red[tid + s];
        __syncthreads();
    }
    return red[0];
}

__device__ inline void bar_arrive(uint_t* cnt) {
    __syncthreads();
    if (threadIdx.x == 0)
        __hip_atomic_fetch_add(cnt, 1u, __ATOMIC_RELEASE, __HIP_MEMORY_SCOPE_AGENT);
}
__device__ inline void bar_wait(uint_t* cnt, uint_t tgt) {
    if (threadIdx.x == 0) {
        while (__hip_atomic_load(cnt, __ATOMIC_ACQUIRE, __HIP_MEMORY_SCOPE_AGENT) < tgt)
            __builtin_amdgcn_s_sleep(2);
    }
    __syncthreads();
}
__device__ inline float aload(const float* p) {
    return __hip_atomic_load(p, __ATOMIC_RELAXED, __HIP_MEMORY_SCOPE_AGENT);
}
__device__ inline void astore(float* p, float v) {
    __hip_atomic_store(p, v, __ATOMIC_RELAXED, __HIP_MEMORY_SCOPE_AGENT);
}

// ---------- prep: bf16 A layouts + zero barrier counter (kernel boundary = visibility) ----------
__global__ __launch_bounds__(256) void k_pre(
    const float* __restrict__ Ar, const float* __restrict__ Ai,
    const float* __restrict__ Dr, const float* __restrict__ Di,
    ushort_t* __restrict__ Abr, ushort_t* __restrict__ Abi,
    ushort_t* __restrict__ ATr, ushort_t* __restrict__ ATi,
    ushort_t* __restrict__ DTr, ushort_t* __restrict__ DTi,
    uint_t* __restrict__ cnt)
{
    const int gt = blockIdx.x * 256 + threadIdx.x;
    const int gs = gridDim.x * 256;
    if (gt == 0) *cnt = 0u;
    for (int idx = gt; idx < L_ * 512 * 64; idx += gs) {
        int l = idx >> 15, rem = idx & 32767;
        int t = rem >> 6, c = rem & 63;
        float vr = 0.f, vi = 0.f;
        if (c < 48) { int g = l * 24576 + t * 48 + c; vr = Ar[g]; vi = Ai[g]; }
        Abr[idx] = f2bf(vr); Abi[idx] = f2bf(vi);
    }
    for (int idx = gt; idx < L_ * 48 * 512; idx += gs) {
        int l = idx / 24576, rem = idx - l * 24576;
        int f = rem >> 9, t = rem & 511;
        int g = l * 24576 + t * 48 + f;
        ATr[idx] = f2bf(Ar[g]); ATi[idx] = f2bf(Ai[g]);
    }
    for (int idx = gt; idx < 48 * 512; idx += gs) {
        int f = idx >> 9, t = idx & 511;
        DTr[idx] = f2bf(Dr[t * 48 + f]); DTi[idx] = f2bf(Di[t * 48 + f]);
    }
}

// ---------- persistent cooperative kernel: all 8 layers + final DFT ----------
// 256 blocks x 256 threads, block owns rows [blk*32, +32); z (fp32) and H (bf16) in LDS.
__global__ __launch_bounds__(256, 1) void k_lamp(
    const float* __restrict__ u,
    const ushort_t* __restrict__ Abr, const ushort_t* __restrict__ Abi,
    const ushort_t* __restrict__ ATr, const ushort_t* __restrict__ ATi,
    const ushort_t* __restrict__ DTr, const ushort_t* __restrict__ DTi,
    const float* __restrict__ th,
    float* part_sig, float* part_r, float* part_i, uint_t* cnt,
    float* __restrict__ out)
{
    extern __shared__ char dyn[];
    float*    pR   = (float*)dyn;                 // [4][6][16][17]  26112 B
    float*    pI   = pR + 4 * 6 * 16 * 17;        // 26112 B
    float*    zreL = pI + 4 * 6 * 16 * 17;        // 6656 B
    float*    zimL = zreL + RPB * ZS;             // 6656 B
    float*    red  = zimL + RPB * ZS;             // 1024 B
    ushort_t* HreL = (ushort_t*)(red + 256);      // 33280 B
    ushort_t* HimL = HreL + RPB * HST;            // 33280 B -> total 133120 B

    const int tid = threadIdx.x, blk = blockIdx.x;
    const int row0 = blk * RPB;
    const int wave = tid >> 6, lane = tid & 63;
    const int quad = lane >> 4, m = lane & 15;
    const int rows16 = (wave >> 1) * 16, tbase = (wave & 1) * 256;
    const float2* u2 = (const float2*)u;
    uint_t tgt = 0;

    // prologue: u -> z LDS, sigma partial
    float acc = 0.f;
    for (int idx = tid; idx < RPB * F_; idx += 256) {
        int r = idx / 48, c = idx - r * 48;
        float2 v = u2[(row0 + r) * 48 + c];
        zreL[r * ZS + c] = v.x; zimL[r * ZS + c] = v.y;
        acc += v.x * v.x + v.y * v.y;
    }
    float s0 = blk_reduce(acc, red);
    if (tid == 0) astore(&part_sig[blk], s0);
    bar_arrive(cnt); tgt += NBLK;

    for (int l = 0; l < L_; ++l) {
        const ushort_t* Abrl = Abr + (size_t)l * T_ * 64;
        const ushort_t* Abil = Abi + (size_t)l * T_ * 64;
        // z A-frags from LDS fp32 (K=48 padded to 64)
        const int zrow = rows16 + m;
        const float* zpr = zreL + zrow * ZS;
        const float* zpi = zimL + zrow * ZS;
        short8 zr0 = pack8(*(const float4*)(zpr + quad * 8), *(const float4*)(zpr + quad * 8 + 4));
        short8 zi0 = pack8(*(const float4*)(zpi + quad * 8), *(const float4*)(zpi + quad * 8 + 4));
        short8 zr1 = {0,0,0,0,0,0,0,0}, zi1 = {0,0,0,0,0,0,0,0};
        if (quad < 2) {
            zr1 = pack8(*(const float4*)(zpr + 32 + quad * 8), *(const float4*)(zpr + 36 + quad * 8));
            zi1 = pack8(*(const float4*)(zpi + 32 + quad * 8), *(const float4*)(zpi + 36 + quad * 8));
        }
        short8 zin0 = negbf(zi0), zin1 = negbf(zi1);

        // sigma barrier + combine (all blocks compute identical sum -> deterministic)
        bar_wait(cnt, tgt);
        float ssum = blk_reduce(aload(&part_sig[tid]), red);
        const float lam = th[l * 3] * sqrtf(ssum * (1.0f / 48.0f));
        const float th1 = th[l * 3 + 1];

        // forward GEMM + fused activation epilogue (H in LDS)
        float cr = 0.f, ci = 0.f;
        for (int ct = 0; ct < 16; ++ct) {
            const int t0 = tbase + ct * 16;
            const ushort_t* ap  = Abrl + (size_t)(t0 + m) * 64 + quad * 8;
            const ushort_t* aip = Abil + (size_t)(t0 + m) * 64 + quad * 8;
            short8 ar0 = *(const short8*)ap;
            short8 ar1 = *(const short8*)(ap + 32);
            short8 ai0 = *(const short8*)aip;
            short8 ai1 = *(const short8*)(aip + 32);
            f32x4 accR = {0.f,0.f,0.f,0.f}, accI = {0.f,0.f,0.f,0.f};
            accR = MFMA(zr0, ar0, accR);
            accR = MFMA(zr1, ar1, accR);
            accR = MFMA(zin0, ai0, accR);
            accR = MFMA(zin1, ai1, accR);
            accI = MFMA(zr0, ai0, accI);
            accI = MFMA(zr1, ai1, accI);
            accI = MFMA(zi0, ar0, accI);
            accI = MFMA(zi1, ar1, accI);
            const int t = t0 + m;
            #pragma unroll
            for (int reg = 0; reg < 4; ++reg) {
                const int lr = rows16 + quad * 4 + reg;
                float Rr = accR[reg], Ri = accI[reg];
                if (l > 0) { Rr += bf2f(HreL[lr * HST + t]); Ri += bf2f(HimL[lr * HST + t]); }
                float mr = fabsf(Rr), mi = fabsf(Ri);
                float fr = th1 * copysignf(fmaxf(mr - lam, 0.f), Rr);
                float fi = th1 * copysignf(fmaxf(mi - lam, 0.f), Ri);
                if (l < L_ - 1) { cr += (mr > lam) ? 1.f : 0.f; ci += (mi > lam) ? 1.f : 0.f; }
                HreL[lr * HST + t] = f2bf(fr);
                HimL[lr * HST + t] = f2bf(fi);
            }
        }

        if (l == L_ - 1) break;

        // count partials -> arrive (overlaps with backward GEMM below)
        float csr = blk_reduce(cr, red);
        if (tid == 0) astore(&part_r[blk], csr);
        float csi = blk_reduce(ci, red);
        if (tid == 0) astore(&part_i[blk], csi);
        bar_arrive(cnt); tgt += NBLK;

        // backward GEMM: h = Hn @ A, K split across waves (this wave: K in [wave*128,+128))
        const ushort_t* ATrl = ATr + (size_t)l * F_ * T_;
        const ushort_t* ATil = ATi + (size_t)l * F_ * T_;
        f32x4 aR[6], aI[6];
        #pragma unroll
        for (int q = 0; q < 6; ++q) { aR[q] = (f32x4){0,0,0,0}; aI[q] = (f32x4){0,0,0,0}; }
        const int kb = wave * 128;
        #pragma unroll
        for (int ks = 0; ks < 4; ++ks) {
            const int k0 = kb + ks * 32 + quad * 8;
            short8 brv[3], biv[3];
            #pragma unroll
            for (int ft = 0; ft < 3; ++ft) {
                brv[ft] = *(const short8*)(ATrl + (size_t)(ft * 16 + m) * T_ + k0);
                biv[ft] = *(const short8*)(ATil + (size_t)(ft * 16 + m) * T_ + k0);
            }
            #pragma unroll
            for (int rt = 0; rt < 2; ++rt) {
                short8 hr = *(const short8*)&HreL[(rt * 16 + m) * HST + k0];
                short8 hi = *(const short8*)&HimL[(rt * 16 + m) * HST + k0];
                short8 hin = negbf(hi);
                #pragma unroll
                for (int ft = 0; ft < 3; ++ft) {
                    const int q = rt * 3 + ft;
                    aR[q] = MFMA(hr, brv[ft], aR[q]);
                    aR[q] = MFMA(hin, biv[ft], aR[q]);
                    aI[q] = MFMA(hr, biv[ft], aI[q]);
                    aI[q] = MFMA(hi, brv[ft], aI[q]);
                }
            }
        }
        // K-partials to LDS
        #pragma unroll
        for (int q = 0; q < 6; ++q) {
            #pragma unroll
            for (int reg = 0; reg < 4; ++reg) {
                pR[((wave * 6 + q) * 16 + quad * 4 + reg) * 17 + m] = aR[q][reg];
                pI[((wave * 6 + q) * 16 + quad * 4 + reg) * 17 + m] = aI[q][reg];
            }
        }
        // b barrier (syncthreads inside also publishes the partials block-wide)
        bar_wait(cnt, tgt);
        float bsr = blk_reduce(aload(&part_r[tid]), red);
        const float bre = th1 * bsr * (1.0f / 48.0f);
        float bsi = blk_reduce(aload(&part_i[tid]), red);
        const float bim = th1 * bsi * (1.0f / 48.0f);
        // z update + sigma partial
        float nrm = 0.f;
        #pragma unroll
        for (int k6 = 0; k6 < 6; ++k6) {
            const int j = tid + k6 * 256;
            const int r = j / 48, f = j - r * 48;
            const int rt = r >> 4, lr = r & 15, ft = f >> 4, c = f & 15;
            float hR = 0.f, hI = 0.f;
            #pragma unroll
            for (int w = 0; w < 4; ++w) {
                hR += pR[((w * 6 + rt * 3 + ft) * 16 + lr) * 17 + c];
                hI += pI[((w * 6 + rt * 3 + ft) * 16 + lr) * 17 + c];
            }
            float2 uv = u2[(row0 + r) * 48 + f];
            float zr = zreL[r * ZS + f], zi = zimL[r * ZS + f];
            float znr = uv.x - hR + bre * zr;
            float zni = uv.y - hI + bim * zi;
            zreL[r * ZS + f] = znr; zimL[r * ZS + f] = zni;
            nrm += znr * znr + zni * zni;
        }
        float ns = blk_reduce(nrm, red);
        if (tid == 0) astore(&part_sig[blk], ns);
        bar_arrive(cnt); tgt += NBLK;
    }

    // final: out = Hn(LDS) @ DFT
    __syncthreads();
    f32x4 fR[6], fI[6];
    #pragma unroll
    for (int q = 0; q < 6; ++q) { fR[q] = (f32x4){0,0,0,0}; fI[q] = (f32x4){0,0,0,0}; }
    const int kb = wave * 128;
    #pragma unroll
    for (int ks = 0; ks < 4; ++ks) {
        const int k0 = kb + ks * 32 + quad * 8;
        short8 brv[3], biv[3];
        #pragma unroll
        for (int ft = 0; ft < 3; ++ft) {
            brv[ft] = *(const short8*)(DTr + (size_t)(ft * 16 + m) * T_ + k0);
            biv[ft] = *(const short8*)(DTi + (size_t)(ft * 16 + m) * T_ + k0);
        }
        #pragma unroll
        for (int rt = 0; rt < 2; ++rt) {
            short8 hr = *(const short8*)&HreL[(rt * 16 + m) * HST + k0];
            short8 hi = *(const short8*)&HimL[(rt * 16 + m) * HST + k0];
            short8 hin = negbf(hi);
            #pragma unroll
            for (int ft = 0; ft < 3; ++ft) {
                const int q = rt * 3 + ft;
                fR[q] = MFMA(hr, brv[ft], fR[q]);
                fR[q] = MFMA(hin, biv[ft], fR[q]);
                fI[q] = MFMA(hr, biv[ft], fI[q]);
                fI[q] = MFMA(hi, brv[ft], fI[q]);
            }
        }
    }
    #pragma unroll
    for (int q = 0; q < 6; ++q) {
        #pragma unroll
        for (int reg = 0; reg < 4; ++reg) {
            pR[((wave * 6 + q) * 16 + quad * 4 + reg) * 17 + m] = fR[q][reg];
            pI[((wave * 6 + q) * 16 + quad * 4 + reg) * 17 + m] = fI[q][reg];
        }
    }
    __syncthreads();
    float2* out2 = (float2*)out;
    #pragma unroll
    for (int k6 = 0; k6 < 6; ++k6) {
        const int j = tid + k6 * 256;
        const int r = j / 48, f = j - r * 48;
        const int rt = r >> 4, lr = r & 15, ft = f >> 4, c = f & 15;
        float hR = 0.f, hI = 0.f;
        #pragma unroll
        for (int w = 0; w < 4; ++w) {
            hR += pR[((w * 6 + rt * 3 + ft) * 16 + lr) * 17 + c];
            hI += pI[((w * 6 + rt * 3 + ft) * 16 + lr) * 17 + c];
        }
        out2[(row0 + r) * 48 + f] = make_float2(hR, hI);
    }
}

extern "C" void kernel_launch(void* const* d_in, const int* in_sizes, int n_in,
                              void* d_out, int out_size, void* d_ws, size_t ws_size,
                              hipStream_t stream) {
    (void)in_sizes; (void)n_in; (void)out_size; (void)ws_size;
    const float* u  = (const float*)d_in[0];
    const float* Ar = (const float*)d_in[1];
    const float* Ai = (const float*)d_in[2];
    const float* th = (const float*)d_in[3];
    const float* Dr = (const float*)d_in[4];
    const float* Di = (const float*)d_in[5];
    float* out = (float*)d_out;

    char* p = (char*)d_ws;
    auto alloc = [&](size_t bytes) -> char* {
        char* r = p;
        p += (bytes + 255) & ~(size_t)255;
        return r;
    };
    float*    part_sig = (float*)alloc(NBLK * 4);
    float*    part_r   = (float*)alloc(NBLK * 4);
    float*    part_i   = (float*)alloc(NBLK * 4);
    uint_t*   cnt      = (uint_t*)alloc(64);
    ushort_t* Abr = (ushort_t*)alloc((size_t)L_ * 512 * 64 * 2);
    ushort_t* Abi = (ushort_t*)alloc((size_t)L_ * 512 * 64 * 2);
    ushort_t* ATr = (ushort_t*)alloc((size_t)L_ * 48 * 512 * 2);
    ushort_t* ATi = (ushort_t*)alloc((size_t)L_ * 48 * 512 * 2);
    ushort_t* DTr = (ushort_t*)alloc((size_t)48 * 512 * 2);
    ushort_t* DTi = (ushort_t*)alloc((size_t)48 * 512 * 2);

    k_pre<<<256, 256, 0, stream>>>(Ar, Ai, Dr, Di, Abr, Abi, ATr, ATi, DTr, DTi, cnt);

    const uint_t lds_bytes = 133120;
    hipFuncSetAttribute((const void*)k_lamp,
                        hipFuncAttributeMaxDynamicSharedMemorySize, (int)lds_bytes);
    void* args[] = { (void*)&u, (void*)&Abr, (void*)&Abi, (void*)&ATr, (void*)&ATi,
                     (void*)&DTr, (void*)&DTi, (void*)&th,
                     (void*)&part_sig, (void*)&part_r, (void*)&part_i,
                     (void*)&cnt, (void*)&out };
    hipLaunchCooperativeKernel((void*)k_lamp, dim3(NBLK), dim3(256), args,
                               lds_bytes, stream);
}

// Round 5
// 255.869 us; speedup vs baseline: 5.4774x; 1.4122x over previous
//
#include <hip/hip_runtime.h>
#include <hip/hip_bf16.h>
#include <math.h>

#define B_   8192
#define F_   48
#define T_   512
#define L_   8
#define NBLK 256
#define THR  512
#define NW   8           // waves per block
#define RPB  32          // rows per block
#define HST  520         // H LDS row stride in shorts (1040B; 65 uint4)
#define ZS   52          // z LDS row stride in floats

typedef unsigned short ushort_t;
typedef unsigned int   uint_t;
typedef __attribute__((ext_vector_type(8))) short short8;
typedef __attribute__((ext_vector_type(4))) float f32x4;

#define MFMA(a,b,c) __builtin_amdgcn_mfma_f32_16x16x32_bf16(a,b,c,0,0,0)

__device__ inline ushort_t f2bf(float x) {
    __hip_bfloat16 h = __float2bfloat16(x);
    return *reinterpret_cast<ushort_t*>(&h);
}
__device__ inline float bf2f(ushort_t x) {
    __hip_bfloat16 h;
    *reinterpret_cast<ushort_t*>(&h) = x;
    return __bfloat162float(h);
}
__device__ inline short8 negbf(short8 v) {
    short8 r;
    #pragma unroll
    for (int i = 0; i < 8; ++i) r[i] = v[i] ^ (short)0x8000;
    return r;
}
__device__ inline short8 pack8(float4 a, float4 b) {
    short8 r;
    r[0]=(short)f2bf(a.x); r[1]=(short)f2bf(a.y); r[2]=(short)f2bf(a.z); r[3]=(short)f2bf(a.w);
    r[4]=(short)f2bf(b.x); r[5]=(short)f2bf(b.y); r[6]=(short)f2bf(b.z); r[7]=(short)f2bf(b.w);
    return r;
}

// block-wide sum: wave butterfly + 8-slot LDS combine (2 syncthreads)
__device__ inline float blk_sum(float v, float* red8) {
    #pragma unroll
    for (int s = 32; s > 0; s >>= 1) v += __shfl_xor(v, s, 64);
    __syncthreads();                       // protect previous red8 use
    if ((threadIdx.x & 63) == 0) red8[threadIdx.x >> 6] = v;
    __syncthreads();
    float t = 0.f;
    #pragma unroll
    for (int w = 0; w < NW; ++w) t += red8[w];
    return t;
}

__device__ inline void bar_add(uint_t* cnt) {
    __hip_atomic_fetch_add(cnt, 1u, __ATOMIC_RELEASE, __HIP_MEMORY_SCOPE_AGENT);
}
__device__ inline void bar_wait(uint_t* cnt, uint_t tgt) {
    if (threadIdx.x == 0) {
        while (__hip_atomic_load(cnt, __ATOMIC_RELAXED, __HIP_MEMORY_SCOPE_AGENT) < tgt)
            __builtin_amdgcn_s_sleep(2);
        (void)__hip_atomic_load(cnt, __ATOMIC_ACQUIRE, __HIP_MEMORY_SCOPE_AGENT);
    }
    __syncthreads();
}
__device__ inline float aload(const float* p) {
    return __hip_atomic_load(p, __ATOMIC_RELAXED, __HIP_MEMORY_SCOPE_AGENT);
}
__device__ inline void astore(float* p, float v) {
    __hip_atomic_store(p, v, __ATOMIC_RELAXED, __HIP_MEMORY_SCOPE_AGENT);
}

// soft-threshold on a packed bf16 pair
__device__ inline uint_t act2(uint_t v, float lam, float th1, float& cnt_) {
    float lo = __uint_as_float(v << 16);
    float hi = __uint_as_float(v & 0xffff0000u);
    float ml = fabsf(lo), mh = fabsf(hi);
    float fl = th1 * copysignf(fmaxf(ml - lam, 0.f), lo);
    float fh = th1 * copysignf(fmaxf(mh - lam, 0.f), hi);
    cnt_ += ((ml > lam) ? 1.f : 0.f) + ((mh > lam) ? 1.f : 0.f);
    return ((uint_t)f2bf(fl)) | (((uint_t)f2bf(fh)) << 16);
}

// ---------- prep: frag-linear bf16 layouts + zero barrier counter ----------
// Af: [L][tile32][k2(2)][quad4][m16][8]  (fwd B-frags; wave reads 1KiB contiguous)
// At: [L][ft3][ks16][quad4][m16][8]      (bwd B-frags)
// Df: [ft3][ks16][quad4][m16][8]         (final B-frags)
__global__ __launch_bounds__(256) void k_pre(
    const float* __restrict__ Ar, const float* __restrict__ Ai,
    const float* __restrict__ Dr, const float* __restrict__ Di,
    ushort_t* __restrict__ Afr, ushort_t* __restrict__ Afi,
    ushort_t* __restrict__ Atr, ushort_t* __restrict__ Ati,
    ushort_t* __restrict__ Dfr, ushort_t* __restrict__ Dfi,
    uint_t* __restrict__ cnt)
{
    const int gt = blockIdx.x * 256 + threadIdx.x;
    const int gs = gridDim.x * 256;
    if (gt == 0) *cnt = 0u;
    for (int idx = gt; idx < L_ * 32768; idx += gs) {
        int j = idx & 7, rest = idx >> 3;
        int mm = rest & 15; rest >>= 4;
        int qq = rest & 3;  rest >>= 2;
        int k2 = rest & 1;  rest >>= 1;
        int tile = rest & 31;
        int l = rest >> 5;
        int t = tile * 16 + mm, k = k2 * 32 + qq * 8 + j;
        float vr = 0.f, vi = 0.f;
        if (k < 48) { int g = l * 24576 + t * 48 + k; vr = Ar[g]; vi = Ai[g]; }
        Afr[idx] = f2bf(vr); Afi[idx] = f2bf(vi);
    }
    for (int idx = gt; idx < L_ * 24576; idx += gs) {
        int j = idx & 7, rest = idx >> 3;
        int mm = rest & 15; rest >>= 4;
        int qq = rest & 3;  rest >>= 2;
        int ks = rest & 15; rest >>= 4;
        int ft = rest % 3;
        int l = rest / 3;
        int f = ft * 16 + mm, k = ks * 32 + qq * 8 + j;
        int g = l * 24576 + k * 48 + f;
        Atr[idx] = f2bf(Ar[g]); Ati[idx] = f2bf(Ai[g]);
    }
    for (int idx = gt; idx < 24576; idx += gs) {
        int j = idx & 7, rest = idx >> 3;
        int mm = rest & 15; rest >>= 4;
        int qq = rest & 3;  rest >>= 2;
        int ks = rest & 15;
        int ft = rest >> 4;
        int f = ft * 16 + mm, k = ks * 32 + qq * 8 + j;
        Dfr[idx] = f2bf(Dr[k * 48 + f]); Dfi[idx] = f2bf(Di[k * 48 + f]);
    }
}

// ---------- persistent cooperative kernel ----------
// 256 blocks x 512 threads; block owns rows [blk*32,+32); z fp32 + H bf16 in LDS.
__global__ __launch_bounds__(THR, 2) void k_lamp(
    const float* __restrict__ u,
    const ushort_t* __restrict__ Afr, const ushort_t* __restrict__ Afi,
    const ushort_t* __restrict__ Atr, const ushort_t* __restrict__ Ati,
    const ushort_t* __restrict__ Dfr, const ushort_t* __restrict__ Dfi,
    const float* __restrict__ th,
    float* part_sig, float* part_r, float* part_i, uint_t* cnt,
    float* __restrict__ out)
{
    extern __shared__ char dyn[];
    float*    pR   = (float*)dyn;                  // [8][3][16][17] 26112 B
    float*    pI   = pR + 8 * 3 * 16 * 17;         // 26112 B
    float*    zreL = pI + 8 * 3 * 16 * 17;         // 6656 B
    float*    zimL = zreL + RPB * ZS;              // 6656 B
    float*    red8 = zimL + RPB * ZS;              // 64 B
    ushort_t* HreL = (ushort_t*)(red8 + 16);       // 33280 B
    ushort_t* HimL = HreL + RPB * HST;             // 33280 B  => 132160 B

    const int tid = threadIdx.x, blk = blockIdx.x;
    const int row0 = blk * RPB;
    const int wave = tid >> 6, lane = tid & 63;
    const int quad = lane >> 4, m = lane & 15;
    const int rows16 = (wave >> 2) * 16;           // fwd: which 16-row tile
    const int rt = wave >> 2, kq = wave & 3;       // bwd: row-tile / K-quarter
    const float2* u2 = (const float2*)u;
    uint_t tgt = 0;

    // prologue: u -> z LDS, sigma partial
    float acc = 0.f;
    #pragma unroll
    for (int k3 = 0; k3 < 3; ++k3) {
        int j = tid + k3 * THR;
        int r = j / 48, c = j - r * 48;
        float2 v = u2[(row0 + r) * 48 + c];
        zreL[r * ZS + c] = v.x; zimL[r * ZS + c] = v.y;
        acc += v.x * v.x + v.y * v.y;
    }
    float s0 = blk_sum(acc, red8);
    if (tid == 0) { astore(&part_sig[blk], s0); bar_add(cnt); }
    tgt += NBLK;

    for (int l = 0; l < L_; ++l) {
        // z A-frags from LDS fp32 (K=48 padded to 64)
        const float* zpr = zreL + (rows16 + m) * ZS;
        const float* zpi = zimL + (rows16 + m) * ZS;
        short8 zr0 = pack8(*(const float4*)(zpr + quad * 8), *(const float4*)(zpr + quad * 8 + 4));
        short8 zi0 = pack8(*(const float4*)(zpi + quad * 8), *(const float4*)(zpi + quad * 8 + 4));
        short8 zr1 = {0,0,0,0,0,0,0,0}, zi1 = {0,0,0,0,0,0,0,0};
        if (quad < 2) {
            zr1 = pack8(*(const float4*)(zpr + 32 + quad * 8), *(const float4*)(zpr + 36 + quad * 8));
            zi1 = pack8(*(const float4*)(zpi + 32 + quad * 8), *(const float4*)(zpi + 36 + quad * 8));
        }
        short8 zin0 = negbf(zi0), zin1 = negbf(zi1);

        // forward GEMM; store R = Hold + Z to H LDS (activation deferred past barrier)
        const ushort_t* Aflr = Afr + (size_t)l * 32768;
        const ushort_t* Afli = Afi + (size_t)l * 32768;
        for (int ct = 0; ct < 8; ++ct) {
            const int tile = (wave & 3) * 8 + ct;
            const ushort_t* rp = Aflr + (size_t)(tile * 2) * 512 + lane * 8;
            const ushort_t* ip = Afli + (size_t)(tile * 2) * 512 + lane * 8;
            short8 ar0 = *(const short8*)rp;
            short8 ar1 = *(const short8*)(rp + 512);
            short8 ai0 = *(const short8*)ip;
            short8 ai1 = *(const short8*)(ip + 512);
            f32x4 accR = {0.f,0.f,0.f,0.f}, accI = {0.f,0.f,0.f,0.f};
            accR = MFMA(zr0, ar0, accR);
            accR = MFMA(zr1, ar1, accR);
            accR = MFMA(zin0, ai0, accR);
            accR = MFMA(zin1, ai1, accR);
            accI = MFMA(zr0, ai0, accI);
            accI = MFMA(zr1, ai1, accI);
            accI = MFMA(zi0, ar0, accI);
            accI = MFMA(zi1, ar1, accI);
            const int t = tile * 16 + m;
            #pragma unroll
            for (int reg = 0; reg < 4; ++reg) {
                const int lr = rows16 + quad * 4 + reg;
                float Rr = accR[reg], Ri = accI[reg];
                if (l > 0) { Rr += bf2f(HreL[lr * HST + t]); Ri += bf2f(HimL[lr * HST + t]); }
                HreL[lr * HST + t] = f2bf(Rr);
                HimL[lr * HST + t] = f2bf(Ri);
            }
        }

        // sigma barrier (hidden behind the GEMM above) + lambda
        bar_wait(cnt, tgt);
        float ssum = blk_sum((tid < NBLK) ? aload(&part_sig[tid]) : 0.f, red8);
        const float lam = th[l * 3] * sqrtf(ssum * (1.0f / 48.0f));
        const float th1 = th[l * 3 + 1];

        // vectorized activation pass over H LDS (R -> Hn), count partials
        float cr = 0.f, ci = 0.f;
        uint4* Hr4 = (uint4*)HreL;
        uint4* Hi4 = (uint4*)HimL;
        #pragma unroll
        for (int k4 = 0; k4 < 4; ++k4) {
            int j = tid + k4 * THR;          // 0..2047
            int r = j >> 6, c4 = j & 63;     // 64 uint4 of data per row (65 incl pad)
            uint4* pr = Hr4 + r * 65 + c4;
            uint4* pi = Hi4 + r * 65 + c4;
            uint4 xr = *pr, xi = *pi;
            xr.x = act2(xr.x, lam, th1, cr); xr.y = act2(xr.y, lam, th1, cr);
            xr.z = act2(xr.z, lam, th1, cr); xr.w = act2(xr.w, lam, th1, cr);
            xi.x = act2(xi.x, lam, th1, ci); xi.y = act2(xi.y, lam, th1, ci);
            xi.z = act2(xi.z, lam, th1, ci); xi.w = act2(xi.w, lam, th1, ci);
            *pr = xr; *pi = xi;
        }

        if (l == L_ - 1) { __syncthreads(); break; }

        float csr = blk_sum(cr, red8);       // also publishes Hn block-wide
        if (tid == 0) astore(&part_r[blk], csr);
        float csi = blk_sum(ci, red8);
        if (tid == 0) { astore(&part_i[blk], csi); bar_add(cnt); }
        tgt += NBLK;

        // backward GEMM: h = Hn @ A; wave (rt,kq) does rows rt*16..+16, K quarter kq
        const ushort_t* Atlr = Atr + (size_t)l * 24576;
        const ushort_t* Atli = Ati + (size_t)l * 24576;
        f32x4 aR[3], aI[3];
        #pragma unroll
        for (int q = 0; q < 3; ++q) { aR[q] = (f32x4){0,0,0,0}; aI[q] = (f32x4){0,0,0,0}; }
        #pragma unroll
        for (int ks = 0; ks < 4; ++ks) {
            const int ksa = kq * 4 + ks;
            const int k0 = ksa * 32 + quad * 8;
            short8 hr = *(const short8*)&HreL[(rt * 16 + m) * HST + k0];
            short8 hi = *(const short8*)&HimL[(rt * 16 + m) * HST + k0];
            short8 hin = negbf(hi);
            #pragma unroll
            for (int ft = 0; ft < 3; ++ft) {
                short8 br = *(const short8*)(Atlr + (size_t)((ft * 16 + ksa) * 64 + lane) * 8);
                short8 bi = *(const short8*)(Atli + (size_t)((ft * 16 + ksa) * 64 + lane) * 8);
                aR[ft] = MFMA(hr, br, aR[ft]);
                aR[ft] = MFMA(hin, bi, aR[ft]);
                aI[ft] = MFMA(hr, bi, aI[ft]);
                aI[ft] = MFMA(hi, br, aI[ft]);
            }
        }
        #pragma unroll
        for (int ft = 0; ft < 3; ++ft) {
            #pragma unroll
            for (int reg = 0; reg < 4; ++reg) {
                pR[((wave * 3 + ft) * 16 + quad * 4 + reg) * 17 + m] = aR[ft][reg];
                pI[((wave * 3 + ft) * 16 + quad * 4 + reg) * 17 + m] = aI[ft][reg];
            }
        }

        // b barrier (hidden behind backward GEMM); its syncthreads publishes pR/pI
        bar_wait(cnt, tgt);
        float bsr = blk_sum((tid < NBLK) ? aload(&part_r[tid]) : 0.f, red8);
        float bsi = blk_sum((tid < NBLK) ? aload(&part_i[tid]) : 0.f, red8);
        const float bre = th1 * bsr * (1.0f / 48.0f);
        const float bim = th1 * bsi * (1.0f / 48.0f);

        // z update + sigma partial
        float nrm = 0.f;
        #pragma unroll
        for (int k3 = 0; k3 < 3; ++k3) {
            int j = tid + k3 * THR;
            int r = j / 48, f = j - r * 48;
            int rt2 = r >> 4, lr = r & 15, ft = f >> 4, c = f & 15;
            float hR = 0.f, hI = 0.f;
            #pragma unroll
            for (int q = 0; q < 4; ++q) {
                hR += pR[(((rt2 * 4 + q) * 3 + ft) * 16 + lr) * 17 + c];
                hI += pI[(((rt2 * 4 + q) * 3 + ft) * 16 + lr) * 17 + c];
            }
            float2 uv = u2[(row0 + r) * 48 + f];
            float zr = zreL[r * ZS + f], zi = zimL[r * ZS + f];
            float znr = uv.x - hR + bre * zr;
            float zni = uv.y - hI + bim * zi;
            zreL[r * ZS + f] = znr; zimL[r * ZS + f] = zni;
            nrm += znr * znr + zni * zni;
        }
        float ns = blk_sum(nrm, red8);
        if (tid == 0) { astore(&part_sig[blk], ns); bar_add(cnt); }
        tgt += NBLK;
    }

    // final: out = Hn(LDS) @ DFT  (wave (rt,kq), K-split, LDS combine)
    f32x4 fR[3], fI[3];
    #pragma unroll
    for (int q = 0; q < 3; ++q) { fR[q] = (f32x4){0,0,0,0}; fI[q] = (f32x4){0,0,0,0}; }
    #pragma unroll
    for (int ks = 0; ks < 4; ++ks) {
        const int ksa = kq * 4 + ks;
        const int k0 = ksa * 32 + quad * 8;
        short8 hr = *(const short8*)&HreL[(rt * 16 + m) * HST + k0];
        short8 hi = *(const short8*)&HimL[(rt * 16 + m) * HST + k0];
        short8 hin = negbf(hi);
        #pragma unroll
        for (int ft = 0; ft < 3; ++ft) {
            short8 br = *(const short8*)(Dfr + (size_t)((ft * 16 + ksa) * 64 + lane) * 8);
            short8 bi = *(const short8*)(Dfi + (size_t)((ft * 16 + ksa) * 64 + lane) * 8);
            fR[ft] = MFMA(hr, br, fR[ft]);
            fR[ft] = MFMA(hin, bi, fR[ft]);
            fI[ft] = MFMA(hr, bi, fI[ft]);
            fI[ft] = MFMA(hi, br, fI[ft]);
        }
    }
    #pragma unroll
    for (int ft = 0; ft < 3; ++ft) {
        #pragma unroll
        for (int reg = 0; reg < 4; ++reg) {
            pR[((wave * 3 + ft) * 16 + quad * 4 + reg) * 17 + m] = fR[ft][reg];
            pI[((wave * 3 + ft) * 16 + quad * 4 + reg) * 17 + m] = fI[ft][reg];
        }
    }
    __syncthreads();
    float2* out2 = (float2*)out;
    #pragma unroll
    for (int k3 = 0; k3 < 3; ++k3) {
        int j = tid + k3 * THR;
        int r = j / 48, f = j - r * 48;
        int rt2 = r >> 4, lr = r & 15, ft = f >> 4, c = f & 15;
        float hR = 0.f, hI = 0.f;
        #pragma unroll
        for (int q = 0; q < 4; ++q) {
            hR += pR[(((rt2 * 4 + q) * 3 + ft) * 16 + lr) * 17 + c];
            hI += pI[(((rt2 * 4 + q) * 3 + ft) * 16 + lr) * 17 + c];
        }
        out2[(row0 + r) * 48 + f] = make_float2(hR, hI);
    }
}

extern "C" void kernel_launch(void* const* d_in, const int* in_sizes, int n_in,
                              void* d_out, int out_size, void* d_ws, size_t ws_size,
                              hipStream_t stream) {
    (void)in_sizes; (void)n_in; (void)out_size; (void)ws_size;
    const float* u  = (const float*)d_in[0];
    const float* Ar = (const float*)d_in[1];
    const float* Ai = (const float*)d_in[2];
    const float* th = (const float*)d_in[3];
    const float* Dr = (const float*)d_in[4];
    const float* Di = (const float*)d_in[5];
    float* out = (float*)d_out;

    char* p = (char*)d_ws;
    auto alloc = [&](size_t bytes) -> char* {
        char* r = p;
        p += (bytes + 255) & ~(size_t)255;
        return r;
    };
    float*    part_sig = (float*)alloc(NBLK * 4);
    float*    part_r   = (float*)alloc(NBLK * 4);
    float*    part_i   = (float*)alloc(NBLK * 4);
    uint_t*   cnt      = (uint_t*)alloc(64);
    ushort_t* Afr = (ushort_t*)alloc((size_t)L_ * 32768 * 2);
    ushort_t* Afi = (ushort_t*)alloc((size_t)L_ * 32768 * 2);
    ushort_t* Atr = (ushort_t*)alloc((size_t)L_ * 24576 * 2);
    ushort_t* Ati = (ushort_t*)alloc((size_t)L_ * 24576 * 2);
    ushort_t* Dfr = (ushort_t*)alloc((size_t)24576 * 2);
    ushort_t* Dfi = (ushort_t*)alloc((size_t)24576 * 2);

    k_pre<<<256, 256, 0, stream>>>(Ar, Ai, Dr, Di, Afr, Afi, Atr, Ati, Dfr, Dfi, cnt);

    const uint_t lds_bytes = 132160;
    hipFuncSetAttribute((const void*)k_lamp,
                        hipFuncAttributeMaxDynamicSharedMemorySize, (int)lds_bytes);
    void* args[] = { (void*)&u, (void*)&Afr, (void*)&Afi, (void*)&Atr, (void*)&Ati,
                     (void*)&Dfr, (void*)&Dfi, (void*)&th,
                     (void*)&part_sig, (void*)&part_r, (void*)&part_i,
                     (void*)&cnt, (void*)&out };
    hipLaunchCooperativeKernel((void*)k_lamp, dim3(NBLK), dim3(THR), args,
                               lds_bytes, stream);
}